// Round 14
// baseline (16769.498 us; speedup 1.0000x reference)
//
#include <hip/hip_runtime.h>
#include <hip/hip_bf16.h>

#define SEQ 118
#define SQS 32    // sQP/sK stride: packed

typedef __attribute__((ext_vector_type(8))) short short8;
typedef __attribute__((ext_vector_type(4))) float f32x4;

__device__ __forceinline__ f32x4 mfma16(short8 a, short8 b, f32x4 c){
  return __builtin_amdgcn_mfma_f32_16x16x32_bf16(a, b, c, 0, 0, 0);
}
__device__ __forceinline__ float bfr(float x){
  return __bfloat162float(__float2bfloat16(x));
}
__device__ __forceinline__ float rcpf(float x){ return __builtin_amdgcn_rcpf(x); }
__device__ __forceinline__ float fsilu(float z){   // z*sigmoid(z), rcp+exp2
  return z * rcpf(1.f + exp2f(-1.442695041f * z));
}
__device__ __forceinline__ float rsum16(float v){
  v += __shfl_xor(v,1); v += __shfl_xor(v,2); v += __shfl_xor(v,4); v += __shfl_xor(v,8);
  return v;
}
__device__ __forceinline__ float rmax16(float v){
  v = fmaxf(v, __shfl_xor(v,1)); v = fmaxf(v, __shfl_xor(v,2));
  v = fmaxf(v, __shfl_xor(v,4)); v = fmaxf(v, __shfl_xor(v,8));
  return v;
}
__device__ __forceinline__ unsigned pack_bf2(float lo, float hi){
  __hip_bfloat162 h2 = __float22bfloat162_rn(float2{lo, hi});
  unsigned u; __builtin_memcpy(&u, &h2, 4);
  return u;
}
// stride-128 XOR swizzle (16B blocks): phys_block = (col>>3) ^ (row&15).
__device__ __forceinline__ int yadr(int row, int col){
  return row*128 + ((((col >> 3) ^ (row & 15)) << 3) | (col & 7));
}

// Pre-permuted bf16 weights (verified round 7):
//  wq/wk/wv: [h][n][k], n <-> orig col d = 4n + h (input-side to_heads)
//  w2:       [n][k'], k' = h*32 + r, dh = (r>>1)+(r&1)*16, orig k = h*32 + dh
__global__ void prep_kernel(const float* __restrict__ qkv_w,
                            const float* __restrict__ fc2_w,
                            __hip_bfloat16* __restrict__ wbf){
  int i = blockIdx.x * 256 + threadIdx.x;   // 65536 total
  int seg = i >> 14;
  int r   = i & 16383;
  int row = r >> 7;
  int k   = r & 127;
  float v;
  if (seg < 3){
    int h = row >> 5, n = row & 31;
    v = qkv_w[(seg*128 + 4*n + h)*128 + k];
  } else {
    int h = k >> 5, rr = k & 31;
    int dh = (rr >> 1) + (rr & 1)*16;
    v = fc2_w[row*128 + h*32 + dh];
  }
  wbf[i] = __float2bfloat16(v);
}

// Round 14 = round 13's head-pair structure (9 barriers/block) with the g
// loops at unroll 1. Round 13's full unroll made BOTH heads' sc[8] live at
// once -> 128-VGPR blowout -> 6.6 GB spill traffic (the regression). With
// unroll 1, one head's live set (~95 regs, the proven round-8-10 budget) at
// a time; the win is WAVE-level slippage: no barrier between g=0 and g=1,
// so different waves occupy different heads' phases within the interval.
__launch_bounds__(512, 4)
__global__ void fused_kernel(const float* __restrict__ x,
                             const float* __restrict__ fc1_w, const float* __restrict__ fc1_b,
                             const float* __restrict__ qkv_b,
                             const float* __restrict__ fc2_b, const float* __restrict__ fc3_w,
                             const float* __restrict__ fc3_b,
                             const float* __restrict__ ln_g,  const float* __restrict__ ln_b,
                             const __hip_bfloat16* __restrict__ wbf,
                             float* __restrict__ out)
{
  __shared__ __align__(16) char smem[78080];
  __hip_bfloat16* Ybuf = (__hip_bfloat16*)(smem);           // 118x128 swz   30208
  __hip_bfloat16* sQPb = (__hip_bfloat16*)(smem + 30208);   // 2 x 128x32    16384
  __hip_bfloat16* sKb  = (__hip_bfloat16*)(smem + 46592);   // 2 x 118x32    15104
  __hip_bfloat16* sVtb = (__hip_bfloat16*)(smem + 61696);   // 2 x 32x128swz 16384
  // sK OOB rows 118-127: buf0 lands in buf1 (finite bf16 K), buf1 lands in
  // sVt buf0 (finite bf16) -> always causally-masked cols for real rows.

  const __hip_bfloat16* wq  = wbf;
  const __hip_bfloat16* wk  = wbf + 16384;
  const __hip_bfloat16* wvw = wbf + 32768;
  const __hip_bfloat16* w2  = wbf + 49152;

  const int b    = blockIdx.x;
  const int tid  = threadIdx.x;
  const int wv   = tid >> 6;        // wave 0..7
  const int lane = tid & 63;
  const int c    = lane & 15;
  const int quad = lane >> 4;
  const int arow = wv*16 + c;       // this lane's M-row for A/ay fragments

  float o1[4];

  #pragma unroll 1
  for (int p = 0; p < 2; ++p){
    // ---- A fragments for this pass (registers only) ----
    short8 afr[4];
    if (p == 0){
      float xs = (arow < SEQ) ? x[b*SEQ + arow] : 0.f;
      #pragma unroll
      for (int k4 = 0; k4 < 4; k4++){
        int d0 = k4*32 + quad*8;
        short8 fr;
        #pragma unroll
        for (int i = 0; i < 8; i++){
          float z = xs * fc1_w[d0+i] + fc1_b[d0+i];
          float v = fsilu(z);
          if (arow >= SEQ) v = 0.f;             // pad rows exact zero
          fr[i] = (short)__builtin_bit_cast(unsigned short, __float2bfloat16(v));
        }
        afr[k4] = fr;
      }
    } else {
      #pragma unroll
      for (int k4 = 0; k4 < 4; k4++){
        short8 fr = (arow < SEQ) ? *(const short8*)(Ybuf + yadr(arow, k4*32 + quad*8))
                                 : (short8){0,0,0,0,0,0,0,0};   // NaN guard
        afr[k4] = fr;
      }
    }

    #pragma unroll 1
    for (int hp = 0; hp < 2; ++hp){
      // ======== stage Q/K/V for heads 2hp, 2hp+1 into double buffers ======
      #pragma unroll 1
      for (int g = 0; g < 2; ++g){
        const int h = hp*2 + g;
        __hip_bfloat16* sQP = sQPb + g*4096;
        __hip_bfloat16* sK  = sKb  + g*3776;
        __hip_bfloat16* sVt = sVtb + g*4096;
        const float invf = exp2f((float)(4*c + h) * (-0.20762050593045f));

        { // Q & K head GEMMs + RoPE (Q pre-scaled by 1/sqrt(32)/ln2)
          const __hip_bfloat16* wpq = wq + (h*32 + c)*128 + quad*8;
          const __hip_bfloat16* wpk = wk + (h*32 + c)*128 + quad*8;
          f32x4 q0={0,0,0,0}, q1={0,0,0,0}, k0={0,0,0,0}, k1={0,0,0,0};
          #pragma unroll
          for (int k4 = 0; k4 < 4; k4++){
            short8 bq0 = *(const short8*)(wpq + k4*32);
            short8 bq1 = *(const short8*)(wpq + 2048 + k4*32);
            short8 bk0 = *(const short8*)(wpk + k4*32);
            short8 bk1 = *(const short8*)(wpk + 2048 + k4*32);
            q0 = mfma16(afr[k4], bq0, q0);
            q1 = mfma16(afr[k4], bq1, q1);
            k0 = mfma16(afr[k4], bk0, k0);
            k1 = mfma16(afr[k4], bk1, k1);
          }
          const float KSC = 0.25500526963f;   // (1/sqrt(32)) * (1/ln2)
          float bQ0 = qkv_b[      4*c + h], bQ1 = qkv_b[ 64 + 4*c + h];
          float bK0 = qkv_b[128 + 4*c + h], bK1 = qkv_b[192 + 4*c + h];
          #pragma unroll
          for (int j = 0; j < 4; j++){
            int s = wv*16 + quad*4 + j;
            float ang = (float)s * invf;
            float cv = bfr(__cosf(ang)), sv = bfr(__sinf(ang));
            float cvq = cv*KSC, svq = sv*KSC;
            float xq1 = q0[j] + bQ0, xq2 = q1[j] + bQ1;
            float xk1 = k0[j] + bK0, xk2 = k1[j] + bK1;
            *(unsigned*)(sQP + s*SQS + 2*c) = pack_bf2( xq1*cvq + xq2*svq, -xq1*svq + xq2*cvq);
            if (s < SEQ)   // sK has 118 rows
              *(unsigned*)(sK + s*SQS + 2*c) = pack_bf2( xk1*cv + xk2*sv, -xk1*sv + xk2*cv);
          }
        }
        { // V head GEMM -> transposed sVt[dh][s] (swizzled)
          const __hip_bfloat16* wpv = wvw + (h*32 + c)*128 + quad*8;
          f32x4 v0={0,0,0,0}, v1={0,0,0,0};
          #pragma unroll
          for (int k4 = 0; k4 < 4; k4++){
            short8 b0 = *(const short8*)(wpv + k4*32);
            short8 b1 = *(const short8*)(wpv + 2048 + k4*32);
            v0 = mfma16(afr[k4], b0, v0);
            v1 = mfma16(afr[k4], b1, v1);
          }
          float bV0 = qkv_b[256 + 4*c + h], bV1 = qkv_b[320 + 4*c + h];
          int s0 = wv*16 + quad*4;
          *(unsigned*)(sVt + yadr(c,      s0    )) = pack_bf2(v0[0]+bV0, v0[1]+bV0);
          *(unsigned*)(sVt + yadr(c,      s0 + 2)) = pack_bf2(v0[2]+bV0, v0[3]+bV0);
          *(unsigned*)(sVt + yadr(c + 16, s0    )) = pack_bf2(v1[0]+bV1, v1[1]+bV1);
          *(unsigned*)(sVt + yadr(c + 16, s0 + 2)) = pack_bf2(v1[2]+bV1, v1[3]+bV1);
        }
      }
      __syncthreads();   // both heads' Q/K/Vt visible

      // ======== attention: heads sequential, waves slip freely ============
      #pragma unroll 1
      for (int g = 0; g < 2; ++g){
        const int h  = hp*2 + g;
        const int st = g ? (7 - wv) : wv;    // per-wave pair work = 9 tiles
        __hip_bfloat16* sQP = sQPb + g*4096;
        __hip_bfloat16* sK  = sKb  + g*3776;
        __hip_bfloat16* sVt = sVtb + g*4096;

        short8 aq = *(const short8*)(sQP + (st*16 + c)*SQS + quad*8);
        f32x4 sc[8];
        #pragma unroll
        for (int t = 0; t < 8; t++){
          sc[t] = (f32x4){0.f,0.f,0.f,0.f};
          if (t <= st){
            short8 bk = *(const short8*)(sK + (t*16 + c)*SQS + quad*8);
            f32x4 z = {0,0,0,0};
            sc[t] = mfma16(aq, bk, z);
          }
        }
        float rnorm[4];
        #pragma unroll
        for (int j = 0; j < 4; j++){
          float mx = -3.0e38f;
          #pragma unroll
          for (int t = 0; t < 8; t++){
            if (t < st){
              mx = fmaxf(mx, sc[t][j]);
            } else if (t == st){               // diagonal tile: in-tile mask
              float v = (c <= quad*4 + j) ? sc[t][j] : -1.0e9f;
              sc[t][j] = v;
              mx = fmaxf(mx, v);
            }
          }
          mx = rmax16(mx);
          float sum = 0.f;
          #pragma unroll
          for (int t = 0; t < 8; t++) if (t <= st){
            float e = exp2f(sc[t][j] - mx); sc[t][j] = e; sum += e;
          }
          sum = rsum16(sum);
          rnorm[j] = rcpf(sum);                // applied to y after PV
        }

        // P@V in 32-k quarters through sQP strip st (wave-private)
        f32x4 y0 = {0,0,0,0}, y1 = {0,0,0,0};
        auto pv_quarter = [&](int qt, f32x4 pa, f32x4 pb){
          int s0 = st*16 + quad*4;
          #pragma unroll
          for (int j = 0; j < 4; j++){
            sQP[(s0+j)*SQS + c     ] = __float2bfloat16(pa[j]);
            sQP[(s0+j)*SQS + 16 + c] = __float2bfloat16(pb[j]);
          }
          short8 ap  = *(const short8*)(sQP + (st*16 + c)*SQS + quad*8);
          short8 bv0 = *(const short8*)(sVt + yadr(c,      qt*32 + quad*8));
          short8 bv1 = *(const short8*)(sVt + yadr(c + 16, qt*32 + quad*8));
          y0 = mfma16(ap, bv0, y0);
          y1 = mfma16(ap, bv1, y1);
        };
        int qmax = st >> 1;
        pv_quarter(0, sc[0], sc[1]);
        if (qmax >= 1) pv_quarter(1, sc[2], sc[3]);
        if (qmax >= 2) pv_quarter(2, sc[4], sc[5]);
        if (qmax >= 3) pv_quarter(3, sc[6], sc[7]);
        #pragma unroll
        for (int j = 0; j < 4; j++){ y0[j] *= rnorm[j]; y1[j] *= rnorm[j]; }

        { // Y -> Ybuf (swizzled) at this head's k'-slice
          int s0 = st*16 + quad*4;
          #pragma unroll
          for (int j = 0; j < 4; j++)
            if (s0 + j < SEQ)
              *(unsigned*)(Ybuf + yadr(s0 + j, h*32 + 2*c)) = pack_bf2(y0[j], y1[j]);
        }
      }
      __syncthreads();   // pair's K/Vt reads done; hp=1: fences Ybuf for FC2
    }

    // ================= FC2 (once per pass) + silu + LN / readout ==========
    short8 ay[4];
    #pragma unroll
    for (int k4 = 0; k4 < 4; k4++)
      ay[k4] = (arow < SEQ) ? *(const short8*)(Ybuf + yadr(arow, k4*32 + quad*8))
                            : (short8){0,0,0,0,0,0,0,0};
    f32x4 xx[8];
    f32x4 S1 = {0,0,0,0}, S2 = {0,0,0,0}, S3 = {0,0,0,0};
    #pragma unroll 1
    for (int t = 0; t < 8; t++){
      f32x4 acc = {0,0,0,0};
      #pragma unroll
      for (int k4 = 0; k4 < 4; k4++){
        short8 bw = *(const short8*)(w2 + (t*16 + c)*128 + k4*32 + quad*8);
        acc = mfma16(ay[k4], bw, acc);
      }
      float bias = fc2_b[t*16 + c];
      float w3   = fc3_w[t*16 + c];
      #pragma unroll
      for (int j = 0; j < 4; j++){
        float v = fsilu(acc[j] + bias);
        xx[t][j] = v;
        S1[j] += v; S2[j] += v*v; S3[j] += v*w3;
      }
    }
    #pragma unroll
    for (int j = 0; j < 4; j++){
      float s1 = rsum16(S1[j]), s2 = rsum16(S2[j]), s3 = rsum16(S3[j]);
      int s = wv*16 + quad*4 + j;
      if (p == 0){
        float mu  = s1 * (1.f/128.f);
        float var = fmaxf(s2 * (1.f/128.f) - mu*mu, 0.f);
        float rs  = rsqrtf(var + 1e-5f);
        if (s < SEQ){
          #pragma unroll
          for (int t = 0; t < 8; t++){
            int d = t*16 + c;
            Ybuf[yadr(s, d)] = __float2bfloat16((xx[t][j] - mu)*rs*ln_g[d] + ln_b[d]);
          }
        }
        o1[j] = s3;                        // x1 . fc3_w residual readout
      } else {
        if (c == 0 && s < SEQ) out[b*SEQ + s] = o1[j] + s3 + fc3_b[0];
      }
    }
    if (p == 0) __syncthreads();   // fence LN writes before pass-1 afr reads
  }
}

extern "C" void kernel_launch(void* const* d_in, const int* in_sizes, int n_in,
                              void* d_out, int out_size, void* d_ws, size_t ws_size,
                              hipStream_t stream){
  const float* x     = (const float*)d_in[0];
  const float* fc1_w = (const float*)d_in[1];
  const float* fc1_b = (const float*)d_in[2];
  const float* qkv_w = (const float*)d_in[3];
  const float* qkv_b = (const float*)d_in[4];
  const float* fc2_w = (const float*)d_in[5];
  const float* fc2_b = (const float*)d_in[6];
  const float* fc3_w = (const float*)d_in[7];
  const float* fc3_b = (const float*)d_in[8];
  const float* ln_g  = (const float*)d_in[9];
  const float* ln_b  = (const float*)d_in[10];

  __hip_bfloat16* wbf = (__hip_bfloat16*)d_ws;   // 65536 bf16 = 128 KB
  prep_kernel<<<256, 256, 0, stream>>>(qkv_w, fc2_w, wbf);

  const int B = in_sizes[0] / SEQ;               // 8192
  fused_kernel<<<B, 512, 0, stream>>>(x, fc1_w, fc1_b, qkv_b, fc2_b, fc3_w, fc3_b,
                                      ln_g, ln_b, wbf, (float*)d_out);
}

// Round 15
// 2672.728 us; speedup vs baseline: 6.2743x; 6.2743x over previous
//
#include <hip/hip_runtime.h>
#include <hip/hip_bf16.h>

#define SEQ 118
#define YS  136   // Ybuf stride (272 B, 16B-aligned rows)
#define SQS 40    // sQP/sK stride (80 B)
#define SVS 136   // sVt stride

typedef __attribute__((ext_vector_type(8))) short short8;
typedef __attribute__((ext_vector_type(4))) float f32x4;

__device__ __forceinline__ f32x4 mfma16(short8 a, short8 b, f32x4 c){
  return __builtin_amdgcn_mfma_f32_16x16x32_bf16(a, b, c, 0, 0, 0);
}
__device__ __forceinline__ float bfr(float x){
  return __bfloat162float(__float2bfloat16(x));
}
__device__ __forceinline__ float rcpf(float x){ return __builtin_amdgcn_rcpf(x); }
__device__ __forceinline__ float fsilu(float z){   // z*sigmoid(z), rcp+exp2
  return z * rcpf(1.f + exp2f(-1.442695041f * z));
}
__device__ __forceinline__ float rsum16(float v){
  v += __shfl_xor(v,1); v += __shfl_xor(v,2); v += __shfl_xor(v,4); v += __shfl_xor(v,8);
  return v;
}
__device__ __forceinline__ float rmax16(float v){
  v = fmaxf(v, __shfl_xor(v,1)); v = fmaxf(v, __shfl_xor(v,2));
  v = fmaxf(v, __shfl_xor(v,4)); v = fmaxf(v, __shfl_xor(v,8));
  return v;
}
__device__ __forceinline__ unsigned pack_bf2(float lo, float hi){
  __hip_bfloat162 h2 = __float22bfloat162_rn(float2{lo, hi});
  unsigned u; __builtin_memcpy(&u, &h2, 4);
  return u;
}

// Pre-permuted bf16 weights (verified round 7):
//  wq/wk/wv: [h][n][k], n <-> orig col d = 4n + h (input-side to_heads)
//  w2:       [n][k'], k' = h*32 + r, dh = (r>>1)+(r&1)*16, orig k = h*32 + dh
__global__ void prep_kernel(const float* __restrict__ qkv_w,
                            const float* __restrict__ fc2_w,
                            __hip_bfloat16* __restrict__ wbf){
  int i = blockIdx.x * 256 + threadIdx.x;   // 65536 total
  int seg = i >> 14;
  int r   = i & 16383;
  int row = r >> 7;
  int k   = r & 127;
  float v;
  if (seg < 3){
    int h = row >> 5, n = row & 31;
    v = qkv_w[(seg*128 + 4*n + h)*128 + k];
  } else {
    int h = k >> 5, rr = k & 31;
    int dh = (rr >> 1) + (rr & 1)*16;
    v = fc2_w[row*128 + h*32 + dh];
  }
  wbf[i] = __float2bfloat16(v);
}

// Round 15 = round 10 (best known, 2521 us) with ONE change: the FC2 xx[8]
// live range (32 f32/lane held across the whole t-loop) is eliminated by
// recompute. Evidence it was spilling: round 7 (no xx) WRITE=4 MB, VGPR 88;
// rounds 8/10 (xx added) WRITE=176-220 MB, VGPR 64 -> ~24 KB/block scratch.
// Pass A: 32 MFMAs -> S1/S2/S3 sums only. Pass B (p==0 only): re-run the 32
// MFMAs and write LN output directly. +32 MFMAs is noise at 5.7% MfmaUtil.
__launch_bounds__(512, 4)
__global__ void fused_kernel(const float* __restrict__ x,
                             const float* __restrict__ fc1_w, const float* __restrict__ fc1_b,
                             const float* __restrict__ qkv_b,
                             const float* __restrict__ fc2_b, const float* __restrict__ fc3_w,
                             const float* __restrict__ fc3_b,
                             const float* __restrict__ ln_g,  const float* __restrict__ ln_b,
                             const __hip_bfloat16* __restrict__ wbf,
                             float* __restrict__ out)
{
  __shared__ __align__(16) char smem[63328];
  __hip_bfloat16* Ybuf = (__hip_bfloat16*)(smem);           // 118 x 136  32096
  __hip_bfloat16* sQP  = (__hip_bfloat16*)(smem + 32096);   // 128 x 40   10240
  __hip_bfloat16* sK   = (__hip_bfloat16*)(smem + 42336);   // 128 x 40   10240
  __hip_bfloat16* sVt  = (__hip_bfloat16*)(smem + 52576);   //  32 x 136   8704
  float*          sCb  = (float*)        (smem + 61280);    // 512 f32     2048

  const __hip_bfloat16* wq  = wbf;
  const __hip_bfloat16* wk  = wbf + 16384;
  const __hip_bfloat16* wvw = wbf + 32768;
  const __hip_bfloat16* w2  = wbf + 49152;

  const int b    = blockIdx.x;
  const int tid  = threadIdx.x;
  const int wv   = tid >> 6;        // wave 0..7 -> 16-row strip
  const int lane = tid & 63;
  const int c    = lane & 15;
  const int quad = lane >> 4;
  const int arow = wv*16 + c;       // this lane's M-row for A/ay fragments

  { // sCb: fc2_b(0..127) fc3_w(128..255) ln_g(256..383) ln_b(384..511)
    int i = tid;
    if (i < 512){
      float v;
      if      (i < 128) v = fc2_b[i];
      else if (i < 256) v = fc3_w[i-128];
      else if (i < 384) v = ln_g [i-256];
      else              v = ln_b [i-384];
      sCb[i] = v;
    }
  }
  __syncthreads();

  float o1[4];

  #pragma unroll 1
  for (int p = 0; p < 2; ++p){
    // ---- A fragments for this pass (registers only) ----
    short8 afr[4];
    if (p == 0){
      float xs = (arow < SEQ) ? x[b*SEQ + arow] : 0.f;
      #pragma unroll
      for (int k4 = 0; k4 < 4; k4++){
        int d0 = k4*32 + quad*8;
        short8 fr;
        #pragma unroll
        for (int i = 0; i < 8; i++){
          float z = xs * fc1_w[d0+i] + fc1_b[d0+i];
          float v = fsilu(z);
          if (arow >= SEQ) v = 0.f;             // pad rows exact zero
          fr[i] = (short)__builtin_bit_cast(unsigned short, __float2bfloat16(v));
        }
        afr[k4] = fr;
      }
    } else {
      #pragma unroll
      for (int k4 = 0; k4 < 4; k4++){
        short8 fr = (arow < SEQ) ? *(const short8*)(Ybuf + arow*YS + k4*32 + quad*8)
                                 : (short8){0,0,0,0,0,0,0,0};   // NaN guard
        afr[k4] = fr;
      }
    }

    #pragma unroll 1
    for (int h = 0; h < 4; ++h){
      const float invf = exp2f((float)(4*c + h) * (-0.20762050593045f)); // 10000^(-d/64)

      { // ---- Q & K head GEMMs + RoPE -> sQP / sK (packed pair k-order) ----
        // Q pre-scaled by KSC = 1/sqrt(32)/ln2: softmax is pure exp2.
        const __hip_bfloat16* wpq = wq + (h*32 + c)*128 + quad*8;
        const __hip_bfloat16* wpk = wk + (h*32 + c)*128 + quad*8;
        f32x4 q0={0,0,0,0}, q1={0,0,0,0}, k0={0,0,0,0}, k1={0,0,0,0};
        #pragma unroll
        for (int k4 = 0; k4 < 4; k4++){
          short8 bq0 = *(const short8*)(wpq + k4*32);
          short8 bq1 = *(const short8*)(wpq + 2048 + k4*32);
          short8 bk0 = *(const short8*)(wpk + k4*32);
          short8 bk1 = *(const short8*)(wpk + 2048 + k4*32);
          q0 = mfma16(afr[k4], bq0, q0);
          q1 = mfma16(afr[k4], bq1, q1);
          k0 = mfma16(afr[k4], bk0, k0);
          k1 = mfma16(afr[k4], bk1, k1);
        }
        const float KSC = 0.25500526963f;   // (1/sqrt(32)) * (1/ln2)
        float bQ0 = qkv_b[      4*c + h], bQ1 = qkv_b[ 64 + 4*c + h];
        float bK0 = qkv_b[128 + 4*c + h], bK1 = qkv_b[192 + 4*c + h];
        #pragma unroll
        for (int j = 0; j < 4; j++){
          int s = wv*16 + quad*4 + j;
          float ang = (float)s * invf;
          float cv = bfr(__cosf(ang)), sv = bfr(__sinf(ang));
          float cvq = cv*KSC, svq = sv*KSC;
          float xq1 = q0[j] + bQ0, xq2 = q1[j] + bQ1;
          float xk1 = k0[j] + bK0, xk2 = k1[j] + bK1;
          *(unsigned*)(sQP + s*SQS + 2*c) = pack_bf2( xq1*cvq + xq2*svq, -xq1*svq + xq2*cvq);
          *(unsigned*)(sK  + s*SQS + 2*c) = pack_bf2( xk1*cv  + xk2*sv , -xk1*sv  + xk2*cv );
        }
      }
      { // ---- V head GEMM -> transposed sVt[dh][s] ----
        const __hip_bfloat16* wpv = wvw + (h*32 + c)*128 + quad*8;
        f32x4 v0={0,0,0,0}, v1={0,0,0,0};
        #pragma unroll
        for (int k4 = 0; k4 < 4; k4++){
          short8 b0 = *(const short8*)(wpv + k4*32);
          short8 b1 = *(const short8*)(wpv + 2048 + k4*32);
          v0 = mfma16(afr[k4], b0, v0);
          v1 = mfma16(afr[k4], b1, v1);
        }
        float bV0 = qkv_b[256 + 4*c + h], bV1 = qkv_b[320 + 4*c + h];
        int s0 = wv*16 + quad*4;
        *(unsigned*)(sVt + (c   )*SVS + s0    ) = pack_bf2(v0[0]+bV0, v0[1]+bV0);
        *(unsigned*)(sVt + (c   )*SVS + s0 + 2) = pack_bf2(v0[2]+bV0, v0[3]+bV0);
        *(unsigned*)(sVt + (c+16)*SVS + s0    ) = pack_bf2(v1[0]+bV1, v1[1]+bV1);
        *(unsigned*)(sVt + (c+16)*SVS + s0 + 2) = pack_bf2(v1[2]+bV1, v1[3]+bV1);
      }
      __syncthreads();   // K/Vt visible to all waves

      // ---- QK^T (causal tile skip) + softmax (exp2 domain, Q pre-scaled) ----
      short8 aq = *(const short8*)(sQP + arow*SQS + quad*8);
      f32x4 sc[8];
      #pragma unroll
      for (int t = 0; t < 8; t++){
        sc[t] = (f32x4){0.f,0.f,0.f,0.f};
        if (t <= wv){
          short8 bk = *(const short8*)(sK + (t*16 + c)*SQS + quad*8);
          f32x4 z = {0,0,0,0};
          sc[t] = mfma16(aq, bk, z);
        }
      }
      float rnorm[4];
      #pragma unroll
      for (int j = 0; j < 4; j++){
        float mx = -3.0e38f;
        #pragma unroll
        for (int t = 0; t < 8; t++){
          if (t < wv){                            // sub-diagonal: always valid
            mx = fmaxf(mx, sc[t][j]);
          } else if (t == wv){                    // diagonal tile: in-tile mask
            float v = (c <= quad*4 + j) ? sc[t][j] : -1.0e9f;
            sc[t][j] = v;
            mx = fmaxf(mx, v);
          }
        }
        mx = rmax16(mx);
        float sum = 0.f;
        #pragma unroll
        for (int t = 0; t < 8; t++) if (t <= wv){
          float e = exp2f(sc[t][j] - mx); sc[t][j] = e; sum += e;
        }
        sum = rsum16(sum);
        rnorm[j] = rcpf(sum);                     // applied to y after PV
      }

      // ---- P@V in 32-k quarters through sQP (wave-private; Q is dead) ----
      f32x4 y0 = {0,0,0,0}, y1 = {0,0,0,0};
      auto pv_quarter = [&](int qt, f32x4 pa, f32x4 pb){
        int s0 = wv*16 + quad*4;
        #pragma unroll
        for (int j = 0; j < 4; j++){
          sQP[(s0+j)*SQS + c     ] = __float2bfloat16(pa[j]);
          sQP[(s0+j)*SQS + 16 + c] = __float2bfloat16(pb[j]);
        }
        short8 ap  = *(const short8*)(sQP + arow*SQS + quad*8);
        short8 bv0 = *(const short8*)(sVt + (c   )*SVS + qt*32 + quad*8);
        short8 bv1 = *(const short8*)(sVt + (c+16)*SVS + qt*32 + quad*8);
        y0 = mfma16(ap, bv0, y0);
        y1 = mfma16(ap, bv1, y1);
      };
      int qmax = wv >> 1;
      pv_quarter(0, sc[0], sc[1]);
      if (qmax >= 1) pv_quarter(1, sc[2], sc[3]);
      if (qmax >= 2) pv_quarter(2, sc[4], sc[5]);
      if (qmax >= 3) pv_quarter(3, sc[6], sc[7]);
      #pragma unroll
      for (int j = 0; j < 4; j++){ y0[j] *= rnorm[j]; y1[j] *= rnorm[j]; }

      { // ---- Y -> Ybuf at this head's k'-slice (guarded: 118 rows only) ----
        int s0 = wv*16 + quad*4;
        #pragma unroll
        for (int j = 0; j < 4; j++)
          if (s0 + j < SEQ)
            *(unsigned*)(Ybuf + (s0+j)*YS + h*32 + 2*c) = pack_bf2(y0[j], y1[j]);
      }
      __syncthreads();   // all reads of K/Vt done; also fences Ybuf for FC2
    }

    // ======== FC2: pass A (sums only, no xx array) ========================
    short8 ay[4];
    #pragma unroll
    for (int k4 = 0; k4 < 4; k4++)
      ay[k4] = (arow < SEQ) ? *(const short8*)(Ybuf + arow*YS + k4*32 + quad*8)
                            : (short8){0,0,0,0,0,0,0,0};
    f32x4 S1 = {0,0,0,0}, S2 = {0,0,0,0}, S3 = {0,0,0,0};
    #pragma unroll 1
    for (int t = 0; t < 8; t++){
      f32x4 acc = {0,0,0,0};
      #pragma unroll
      for (int k4 = 0; k4 < 4; k4++){
        short8 bw = *(const short8*)(w2 + (t*16 + c)*128 + k4*32 + quad*8);
        acc = mfma16(ay[k4], bw, acc);
      }
      float bias = sCb[t*16 + c];
      float w3   = sCb[128 + t*16 + c];
      #pragma unroll
      for (int j = 0; j < 4; j++){
        float v = fsilu(acc[j] + bias);
        S1[j] += v; S2[j] += v*v; S3[j] += v*w3;
      }
    }
    float mu[4], rs[4];
    #pragma unroll
    for (int j = 0; j < 4; j++){
      float s1 = rsum16(S1[j]), s2 = rsum16(S2[j]), s3 = rsum16(S3[j]);
      int s = wv*16 + quad*4 + j;
      if (p == 0){
        mu[j] = s1 * (1.f/128.f);
        float var = fmaxf(s2 * (1.f/128.f) - mu[j]*mu[j], 0.f);
        rs[j] = rsqrtf(var + 1e-5f);
        o1[j] = s3;                        // x1 . fc3_w residual readout
      } else {
        if (c == 0 && s < SEQ) out[b*SEQ + s] = o1[j] + s3 + fc3_b[0];
      }
    }
    // ======== FC2: pass B (p==0 only) — recompute + LN writeback ==========
    if (p == 0){
      #pragma unroll 1
      for (int t = 0; t < 8; t++){
        f32x4 acc = {0,0,0,0};
        #pragma unroll
        for (int k4 = 0; k4 < 4; k4++){
          short8 bw = *(const short8*)(w2 + (t*16 + c)*128 + k4*32 + quad*8);
          acc = mfma16(ay[k4], bw, acc);
        }
        float bias = sCb[t*16 + c];
        int d = t*16 + c;
        float g = sCb[256 + d], bb = sCb[384 + d];
        #pragma unroll
        for (int j = 0; j < 4; j++){
          int s = wv*16 + quad*4 + j;
          if (s < SEQ){
            float v = fsilu(acc[j] + bias);
            Ybuf[s*YS + d] = __float2bfloat16((v - mu[j])*rs[j]*g + bb);
          }
        }
      }
      __syncthreads();   // fence LN writes before pass-1 afr reads
    }
  }
}

extern "C" void kernel_launch(void* const* d_in, const int* in_sizes, int n_in,
                              void* d_out, int out_size, void* d_ws, size_t ws_size,
                              hipStream_t stream){
  const float* x     = (const float*)d_in[0];
  const float* fc1_w = (const float*)d_in[1];
  const float* fc1_b = (const float*)d_in[2];
  const float* qkv_w = (const float*)d_in[3];
  const float* qkv_b = (const float*)d_in[4];
  const float* fc2_w = (const float*)d_in[5];
  const float* fc2_b = (const float*)d_in[6];
  const float* fc3_w = (const float*)d_in[7];
  const float* fc3_b = (const float*)d_in[8];
  const float* ln_g  = (const float*)d_in[9];
  const float* ln_b  = (const float*)d_in[10];

  __hip_bfloat16* wbf = (__hip_bfloat16*)d_ws;   // 65536 bf16 = 128 KB
  prep_kernel<<<256, 256, 0, stream>>>(qkv_w, fc2_w, wbf);

  const int B = in_sizes[0] / SEQ;               // 8192
  fused_kernel<<<B, 512, 0, stream>>>(x, fc1_w, fc1_b, qkv_b, fc2_b, fc3_w, fc3_b,
                                      ln_g, ln_b, wbf, (float*)d_out);
}